// Round 15
// baseline (359.609 us; speedup 1.0000x reference)
//
#include <hip/hip_runtime.h>
#include <stdint.h>

#define G1  128   // blocks for hist/scatter passes
#define BSH 9     // log2(nodes per bucket)
#define BSZ 512   // nodes per bucket
// NB = ceil(n/512) must be <= 256 (holds for n <= 131072; here n = 100000 -> 196)

typedef __attribute__((ext_vector_type(8))) _Float16 f16x8;
typedef __attribute__((ext_vector_type(2))) _Float16 f16x2;
typedef __attribute__((ext_vector_type(2))) __fp16 fp16x2r;  // cvt_pkrtz return type
typedef __attribute__((ext_vector_type(4))) float f32x4;

// ---------------- threefry2x32 (JAX-compatible, 20 rounds) ----------------
#define TF_ROUND(x0, x1, r)                                                    \
  {                                                                            \
    x0 += x1;                                                                  \
    x1 = (x1 << r) | (x1 >> (32 - r));                                         \
    x1 ^= x0;                                                                  \
  }

__host__ __device__ inline void threefry2x32(uint32_t k0, uint32_t k1,
                                             uint32_t x0, uint32_t x1,
                                             uint32_t* o0, uint32_t* o1) {
  uint32_t ks2 = k0 ^ k1 ^ 0x1BD11BDAu;
  x0 += k0; x1 += k1;
  TF_ROUND(x0, x1, 13) TF_ROUND(x0, x1, 15) TF_ROUND(x0, x1, 26) TF_ROUND(x0, x1, 6)
  x0 += k1; x1 += ks2 + 1u;
  TF_ROUND(x0, x1, 17) TF_ROUND(x0, x1, 29) TF_ROUND(x0, x1, 16) TF_ROUND(x0, x1, 24)
  x0 += ks2; x1 += k0 + 2u;
  TF_ROUND(x0, x1, 13) TF_ROUND(x0, x1, 15) TF_ROUND(x0, x1, 26) TF_ROUND(x0, x1, 6)
  x0 += k0; x1 += k1 + 3u;
  TF_ROUND(x0, x1, 17) TF_ROUND(x0, x1, 29) TF_ROUND(x0, x1, 16) TF_ROUND(x0, x1, 24)
  x0 += k1; x1 += ks2 + 4u;
  TF_ROUND(x0, x1, 13) TF_ROUND(x0, x1, 15) TF_ROUND(x0, x1, 26) TF_ROUND(x0, x1, 6)
  x0 += ks2; x1 += k0 + 5u;
  *o0 = x0; *o1 = x1;
}

__device__ inline uint32_t tf_bits32(uint32_t k0, uint32_t k1, uint32_t ctr) {
  uint32_t a, b;
  threefry2x32(k0, k1, 0u, ctr, &a, &b);
  return a ^ b;
}

// fp16 helpers
__device__ inline f16x2 u2h(uint32_t u) {
  union { uint32_t u; f16x2 h; } c; c.u = u; return c.h;
}
__device__ inline uint32_t h2u(f16x2 h) {
  union { uint32_t u; f16x2 h; } c; c.h = h; return c.u;
}
__device__ inline uint32_t pk2h(float a, float b) {
  union { fp16x2r h; uint32_t u; } c;
  c.h = __builtin_amdgcn_cvt_pkrtz(a, b);
  return c.u;
}
__device__ inline uint16_t f2h(float a) {
  union { fp16x2r h; uint32_t u; } c;
  c.h = __builtin_amdgcn_cvt_pkrtz(a, 0.f);
  return (uint16_t)c.u;
}

// ---- histogram only: per-block dst-bucket counts -> hist_t[bucket][block] ----
__global__ __launch_bounds__(256) void k_hist(const int* __restrict__ dst,
                                              int* __restrict__ hist_t,
                                              int E, int NB, int chunk) {
  __shared__ int hist[256];
  const int tid = threadIdx.x;
  for (int b = tid; b < NB; b += 256) hist[b] = 0;
  __syncthreads();
  int e0 = blockIdx.x * chunk;
  int e1 = min(e0 + chunk, E);
  for (int e = e0 + tid; e < e1; e += 256)
    atomicAdd(&hist[dst[e] >> BSH], 1);
  __syncthreads();
  for (int b = tid; b < NB; b += 256)
    hist_t[b * G1 + blockIdx.x] = hist[b];
}

// ---- merged: blocks 0..G1-1 = bscatter (self-scan); blocks G1.. = GEMM1 ----
__global__ __launch_bounds__(256) void k_bsc_gemm1(
    const int* __restrict__ src, const int* __restrict__ dst,
    const int* __restrict__ hist_t, int* __restrict__ segs,
    uint32_t* __restrict__ ebuf, int E, int NB, int chunk,
    const float* __restrict__ x, const float* __restrict__ W,
    uint16_t* __restrict__ h, int n) {
  __shared__ char smem[(64 * 136 + 128 * 136) * 2];
  const int tid = threadIdx.x;
  if (blockIdx.x < G1) {
    int* rowsum = (int*)smem;
    int* cur = ((int*)smem) + 256;
    const int g = blockIdx.x;
    int rs = 0, ps = 0;
    if (tid < NB) {
      const int* row = hist_t + tid * G1;
      for (int i = 0; i < G1; ++i) {
        int v = row[i];
        rs += v;
        if (i < g) ps += v;
      }
    }
    rowsum[tid] = rs;
    __syncthreads();
    for (int off = 1; off < 256; off <<= 1) {
      int tmp = (tid >= off) ? rowsum[tid - off] : 0;
      __syncthreads();
      rowsum[tid] += tmp;
      __syncthreads();
    }
    int rb = rowsum[tid] - rs;  // exclusive row base
    if (tid < NB) cur[tid] = rb + ps;
    if (g == 0) {
      if (tid < NB) segs[tid] = rb;
      if (tid == 255) segs[NB] = rowsum[255];  // total = E
    }
    __syncthreads();
    int e0 = g * chunk, e1 = min(e0 + chunk, E);
    for (int e = e0 + tid; e < e1; e += 256) {
      int d = dst[e];
      int slot = atomicAdd(&cur[d >> BSH], 1);
      ebuf[slot] = ((uint32_t)src[e] << BSH) | (uint32_t)(d & (BSZ - 1));
    }
    return;
  }
  // ---- GEMM1 part ----
  uint16_t (*As)[136] = (uint16_t(*)[136])smem;
  uint16_t (*Bs)[136] = (uint16_t(*)[136])(smem + 64 * 136 * 2);
  const int rowBase = (blockIdx.x - G1) * 64;
  for (int i = tid; i < 64 * 32; i += 256) {
    int r = i >> 5, c4 = i & 31;
    float4 v = make_float4(0.f, 0.f, 0.f, 0.f);
    if (rowBase + r < n)
      v = ((const float4*)(x + (size_t)(rowBase + r) * 128))[c4];
    *(uint2*)&As[r][c4 * 4] = make_uint2(pk2h(v.x, v.y), pk2h(v.z, v.w));
  }
  {
    int k2 = tid >> 7;
    int c = tid & 127;
    for (int kk = 0; kk < 128; kk += 4) {
      int k = kk + k2 * 2;
      *(uint32_t*)&Bs[c][k] = pk2h(W[k * 128 + c], W[(k + 1) * 128 + c]);
    }
  }
  __syncthreads();
  const int wid = tid >> 6;
  const int lane = tid & 63;
  const int l15 = lane & 15;
  const int lhi = lane >> 4;
  f32x4 acc[8];
#pragma unroll
  for (int t = 0; t < 8; ++t) acc[t] = (f32x4){0.f, 0.f, 0.f, 0.f};
  const int arow = wid * 16 + l15;
#pragma unroll
  for (int ks = 0; ks < 4; ++ks) {
    f16x8 a = *(f16x8*)&As[arow][ks * 32 + lhi * 8];
#pragma unroll
    for (int ct = 0; ct < 8; ++ct) {
      f16x8 bfrag = *(f16x8*)&Bs[ct * 16 + l15][ks * 32 + lhi * 8];
      acc[ct] = __builtin_amdgcn_mfma_f32_16x16x32_f16(a, bfrag, acc[ct], 0, 0, 0);
    }
  }
#pragma unroll
  for (int j = 0; j < 4; ++j) {
    int row = rowBase + wid * 16 + lhi * 4 + j;
    if (row < n) {
#pragma unroll
      for (int ct = 0; ct < 8; ++ct)
        h[(size_t)row * 128 + ct * 16 + l15] = f2h(acc[ct][j]);
    }
  }
}

__global__ __launch_bounds__(256) void k_bfinal(const uint32_t* __restrict__ ebuf,
                                                const int* __restrict__ segs,
                                                int* __restrict__ rowptr,
                                                float* __restrict__ dis,
                                                int* __restrict__ csrc,
                                                int n, int NB, int E) {
  __shared__ int cnt[BSZ];
  __shared__ int sc[256];
  int b = blockIdx.x;
  int t = threadIdx.x;
  int seg0 = segs[b];
  int seg1 = segs[b + 1];
  for (int i = t; i < BSZ; i += 256) cnt[i] = 0;
  __syncthreads();
  for (int i = seg0 + t; i < seg1; i += 256)
    atomicAdd(&cnt[ebuf[i] & (BSZ - 1)], 1);
  __syncthreads();
  int a0 = cnt[2 * t], a1 = cnt[2 * t + 1];
  int s = a0 + a1;
  sc[t] = s;
  __syncthreads();
  for (int off = 1; off < 256; off <<= 1) {
    int tmp = (t >= off) ? sc[t - off] : 0;
    __syncthreads();
    sc[t] += tmp;
    __syncthreads();
  }
  int pre = sc[t] - s;
  int node0 = b * BSZ;
  int p0 = seg0 + pre;
  int p1 = p0 + a0;
  int nd0 = node0 + 2 * t, nd1 = nd0 + 1;
  if (nd0 <= n) rowptr[nd0] = p0;
  if (nd1 <= n) rowptr[nd1] = p1;
  if (nd0 < n) dis[nd0] = rsqrtf((float)(a0 + 1));
  if (nd1 < n) dis[nd1] = rsqrtf((float)(a1 + 1));
  cnt[2 * t] = p0;
  cnt[2 * t + 1] = p1;
  __syncthreads();
  for (int i = seg0 + t; i < seg1; i += 256) {
    uint32_t u = ebuf[i];
    int slot = atomicAdd(&cnt[u & (BSZ - 1)], 1);
    csrc[slot] = (int)(u >> BSH);
  }
  if (b == NB - 1 && t == 0) rowptr[n] = E;
}

// ---- XCD-sliced layer-1 gather: slice = blockIdx % 8 (16 feats, 3.2MB/XCD-L2).
// 8 lanes/node-group: 4 edge slots x 2 lanes(uint4=8 feats). Fused bias/prelu/
// dropout epilogue; writes post-dropout h (fp16 packed) to hbf.
__global__ __launch_bounds__(256) void k_gslice(
    const int* __restrict__ rowptr, const int* __restrict__ csrc,
    const float* __restrict__ dis, const uint16_t* __restrict__ h1,
    const float* __restrict__ bias, const float* __restrict__ pa,
    uint32_t* __restrict__ hbf, int n, uint32_t k0, uint32_t k1) {
  const int slice = blockIdx.x & 7;
  const int nblk = blockIdx.x >> 3;
  const int tid = threadIdx.x;
  const int grp = tid >> 3;       // node slot 0..31
  const int sub = tid & 7;
  const int q = sub >> 1;         // edge slot 0..3
  const int sl = sub & 1;         // which 16B half of the 32B slice
  const int fo = slice * 16 + sl * 8 + q * 2;  // this lane's output feats
  const float a = pa[0];
  const float bi0 = bias[fo], bi1 = bias[fo + 1];
  const uint4* rowbase = (const uint4*)h1;    // 16 uint4 per 256B row
  const int roff = slice * 2 + sl;            // uint4 index within row
  for (int i = 0; i < 4; ++i) {
    const int v = nblk * 128 + grp * 4 + i;   // uniform across the 8-lane group
    if (v >= n) break;
    uint32_t cc = (uint32_t)v * 128u + (uint32_t)fo;
    uint32_t bits0 = tf_bits32(k0, k1, cc);
    uint32_t bits1 = tf_bits32(k0, k1, cc + 1);
    float dv = dis[v];
    f16x2 acc0 = u2h(0u), acc1 = u2h(0u), acc2 = u2h(0u), acc3 = u2h(0u);
    if (q == 0) {  // self term, weight dv
      uint4 r = rowbase[(size_t)v * 16 + roff];
      f16x2 w = u2h(pk2h(dv, dv));
      acc0 += u2h(r.x) * w; acc1 += u2h(r.y) * w;
      acc2 += u2h(r.z) * w; acc3 += u2h(r.w) * w;
    }
    int beg = rowptr[v];
    int deg = rowptr[v + 1] - beg;
    for (int bb = 0; bb < deg; bb += 8) {
      int cnt = min(8, deg - bb);
      int idx = bb + sub;
      int sv = v;          // padded: own row (hot), zero weight
      uint32_t wpk = 0u;
      if (idx < deg) {
        sv = csrc[beg + idx];
        float wd = dis[sv];
        wpk = pk2h(wd, wd);
      }
      for (int j = 0; j < cnt; j += 4) {
        int s0 = __shfl(sv, j + q, 8);
        uint32_t w0 = (uint32_t)__shfl((int)wpk, j + q, 8);
        uint4 r0 = rowbase[(size_t)s0 * 16 + roff];
        f16x2 hw = u2h(w0);
        acc0 += u2h(r0.x) * hw; acc1 += u2h(r0.y) * hw;
        acc2 += u2h(r0.z) * hw; acc3 += u2h(r0.w) * hw;
      }
    }
    // combine across the 4 edge slots (lanes with same sl: xor 2, xor 4)
#define COMB2(A)                                                               \
  {                                                                            \
    uint32_t u_ = h2u(A);                                                      \
    A = A + u2h((uint32_t)__shfl_xor((int)u_, 2));                             \
    u_ = h2u(A);                                                               \
    A = A + u2h((uint32_t)__shfl_xor((int)u_, 4));                             \
  }
    COMB2(acc0) COMB2(acc1) COMB2(acc2) COMB2(acc3)
#undef COMB2
    f16x2 p = (q == 0) ? acc0 : (q == 1) ? acc1 : (q == 2) ? acc2 : acc3;
    float v0 = (float)p.x * dv + bi0;
    float v1 = (float)p.y * dv + bi1;
    v0 = v0 >= 0.f ? v0 : a * v0;
    v1 = v1 >= 0.f ? v1 : a * v1;
    float r0 = (bits0 & 0x80000000u) ? 0.f : 2.f * v0;
    float r1 = (bits1 & 0x80000000u) ? 0.f : 2.f * v1;
    hbf[(size_t)v * 64 + slice * 8 + sl * 4 + q] = pk2h(r0, r1);
  }
}

// ---- GEMM2 (MFMA f16): h2[n,16] = hbf[n,128] @ f16(W2)  (unscaled, fp16 out) ----
__global__ __launch_bounds__(256) void k_gemm2(const uint32_t* __restrict__ hbf,
                                               const float* __restrict__ W2,
                                               uint32_t* __restrict__ h2, int n) {
  __shared__ uint16_t As[64][136];
  __shared__ uint16_t Bs[16][136];
  const int tid = threadIdx.x;
  const int rowBase = blockIdx.x * 64;
  for (int i = tid; i < 64 * 32; i += 256) {
    int r = i >> 5, c4 = i & 31;
    uint2 v = make_uint2(0u, 0u);
    if (rowBase + r < n)
      v = ((const uint2*)(hbf + (size_t)(rowBase + r) * 64))[c4];
    *(uint2*)&As[r][c4 * 4] = v;
  }
  {
    int c = tid & 15;
    int k8 = tid >> 4;  // 0..15
#pragma unroll
    for (int jj = 0; jj < 8; ++jj) {
      int k = k8 * 8 + jj;
      Bs[c][k] = f2h(W2[k * 16 + c]);
    }
  }
  __syncthreads();
  const int wid = tid >> 6;
  const int lane = tid & 63;
  const int l15 = lane & 15;
  const int lhi = lane >> 4;
  f32x4 acc = (f32x4){0.f, 0.f, 0.f, 0.f};
  const int arow = wid * 16 + l15;
#pragma unroll
  for (int ks = 0; ks < 4; ++ks) {
    f16x8 a = *(f16x8*)&As[arow][ks * 32 + lhi * 8];
    f16x8 bfrag = *(f16x8*)&Bs[l15][ks * 32 + lhi * 8];
    acc = __builtin_amdgcn_mfma_f32_16x16x32_f16(a, bfrag, acc, 0, 0, 0);
  }
#pragma unroll
  for (int j = 0; j < 4; ++j) {
    int row = rowBase + wid * 16 + lhi * 4 + j;
    float val = (row < n) ? acc[j] : 0.f;
    float pv = __shfl_xor(val, 1);  // partner column, same row
    if (row < n && (l15 & 1) == 0)
      h2[(size_t)row * 8 + (l15 >> 1)] = pk2h(val, pv);
  }
}

// ---- gather layer 2: 8 lanes/node, 2 lanes x uint4 per edge (4 edge slots),
// packed-fp16 accs + fused GEMM3 ----
__global__ __launch_bounds__(256) void k_gather2(
    const int* __restrict__ rowptr, const int* __restrict__ csrc,
    const float* __restrict__ dis, const uint32_t* __restrict__ h2,
    const float* __restrict__ bias, const float* __restrict__ pa,
    const float* __restrict__ Wfc, const float* __restrict__ bfc,
    float* __restrict__ out, int n, uint32_t k0, uint32_t k1) {
  __shared__ float wfc[16][10];
  __shared__ float sbfc[10];
  __shared__ float sval[32][16];
  const int tid = threadIdx.x;
  if (tid < 160) ((float*)wfc)[tid] = Wfc[tid];
  if (tid < 10) sbfc[tid] = bfc[tid];
  __syncthreads();
  const int gnode = (blockIdx.x * 256 + tid) >> 3;
  const int grp = tid >> 3;        // node slot in block (0..31)
  const int sub = tid & 7;         // lane within node group
  const int q = sub >> 1;          // edge slot 0..3
  const int sl = sub & 1;          // row half (16B)
  const int f0 = 8 * sl + 2 * q;   // this lane finishes feats f0, f0+1
  const uint4* rowbase = (const uint4*)h2;  // 16B units, 2 per row
  if (gnode < n) {
    uint32_t c0 = (uint32_t)gnode * 16u + (uint32_t)f0;
    uint32_t bits0 = tf_bits32(k0, k1, c0);
    uint32_t bits1 = tf_bits32(k0, k1, c0 + 1);
    float dv = dis[gnode];
    f16x2 acc0 = u2h(0u), acc1 = u2h(0u), acc2 = u2h(0u), acc3 = u2h(0u);
    if (q == 0) {  // self term with weight dv
      uint4 r = rowbase[(size_t)gnode * 2 + sl];
      f16x2 w = u2h(pk2h(dv, dv));
      acc0 += u2h(r.x) * w; acc1 += u2h(r.y) * w;
      acc2 += u2h(r.z) * w; acc3 += u2h(r.w) * w;
    }
    int beg = rowptr[gnode];
    int deg = rowptr[gnode + 1] - beg;
    for (int bb = 0; bb < deg; bb += 8) {
      int cnt = min(8, deg - bb);
      int idx = bb + sub;
      int sv = gnode;       // padded: own row, zero weight
      uint32_t wpk = 0u;
      if (idx < deg) {
        sv = csrc[beg + idx];
        float wd = dis[sv];
        wpk = pk2h(wd, wd);
      }
      for (int j = 0; j < cnt; j += 4) {
        int s0 = __shfl(sv, j + q, 8);
        uint32_t w0 = (uint32_t)__shfl((int)wpk, j + q, 8);
        uint4 r0 = rowbase[(size_t)s0 * 2 + sl];
        f16x2 hw0 = u2h(w0);
        acc0 += u2h(r0.x) * hw0; acc1 += u2h(r0.y) * hw0;
        acc2 += u2h(r0.z) * hw0; acc3 += u2h(r0.w) * hw0;
      }
    }
#define COMB2(A)                                                               \
  {                                                                            \
    uint32_t u_ = h2u(A);                                                      \
    A = A + u2h((uint32_t)__shfl_xor((int)u_, 2));                             \
    u_ = h2u(A);                                                               \
    A = A + u2h((uint32_t)__shfl_xor((int)u_, 4));                             \
  }
    COMB2(acc0) COMB2(acc1) COMB2(acc2) COMB2(acc3)
#undef COMB2
    f16x2 p = (q == 0) ? acc0 : (q == 1) ? acc1 : (q == 2) ? acc2 : acc3;
    float a = pa[0];
    float v0 = (float)p.x * dv + bias[f0];
    float v1 = (float)p.y * dv + bias[f0 + 1];
    v0 = v0 >= 0.f ? v0 : a * v0;
    v1 = v1 >= 0.f ? v1 : a * v1;
    sval[grp][f0]     = (bits0 & 0x80000000u) ? 0.f : 2.f * v0;
    sval[grp][f0 + 1] = (bits1 & 0x80000000u) ? 0.f : 2.f * v1;
  }
  __syncthreads();
  if (gnode < n && sub < 5) {
    int c = sub * 2;
    float o0 = sbfc[c], o1 = sbfc[c + 1];
#pragma unroll
    for (int k = 0; k < 16; ++k) {
      float hv = sval[grp][k];
      o0 += hv * wfc[k][c];
      o1 += hv * wfc[k][c + 1];
    }
    *(float2*)&out[(size_t)gnode * 10 + c] = make_float2(o0, o1);
  }
}

extern "C" void kernel_launch(void* const* d_in, const int* in_sizes, int n_in,
                              void* d_out, int out_size, void* d_ws, size_t ws_size,
                              hipStream_t stream) {
  const float* x   = (const float*)d_in[0];
  const int*   ei  = (const int*)d_in[1];
  const float* W1  = (const float*)d_in[2];
  const float* b1  = (const float*)d_in[3];
  const float* W2  = (const float*)d_in[4];
  const float* b2  = (const float*)d_in[5];
  const float* pa  = (const float*)d_in[6];
  const float* Wfc = (const float*)d_in[7];
  const float* bfc = (const float*)d_in[8];
  float* out = (float*)d_out;

  const int n = in_sizes[0] / 128;
  const int E = in_sizes[1] / 2;
  const int* src = ei;
  const int* dst = ei + E;

  const int NB = (n + BSZ - 1) / BSZ;   // <= 256 required (n <= 131072)
  const int T = NB * G1;
  const int chunk = (E + G1 - 1) / G1;

  char* w = (char*)d_ws;
  auto alloc = [&](size_t bytes) {
    char* p = w;
    w += (bytes + 255) & ~(size_t)255;
    return p;
  };
  float* dis      = (float*)alloc((size_t)n * 4);
  int* rowptr     = (int*)alloc((size_t)(n + 1) * 4);
  int* hist_t     = (int*)alloc((size_t)(T + 1) * 4);
  int* segs       = (int*)alloc((size_t)(NB + 1) * 4);
  uint32_t* ebuf  = (uint32_t*)alloc((size_t)E * 4);
  int* csrc       = (int*)alloc((size_t)E * 4);
  uint16_t* h1f   = (uint16_t*)alloc((size_t)n * 128 * 2);  // fp16 h1 (unscaled)
  uint32_t* hbf   = (uint32_t*)alloc((size_t)n * 64 * 4);   // fp16 h (packed x2)
  uint32_t* h2f   = (uint32_t*)alloc((size_t)n * 8 * 4);    // fp16 h2 (packed x2)

  uint32_t dk1_0, dk1_1, dk2_0, dk2_1;
  threefry2x32(0u, 42u, 0u, 0u, &dk1_0, &dk1_1);
  threefry2x32(0u, 42u, 0u, 1u, &dk2_0, &dk2_1);

  // 1. dst-bucket histogram
  k_hist<<<G1, 256, 0, stream>>>(dst, hist_t, E, NB, chunk);
  // 2. {bscatter (self-scan, emits segs) || gemm1 (unscaled fp16)} one launch
  k_bsc_gemm1<<<G1 + (n + 63) / 64, 256, 0, stream>>>(
      src, dst, hist_t, segs, ebuf, E, NB, chunk, x, W1, h1f, n);
  // 3. finalize: rowptr, dis, csrc
  k_bfinal<<<NB, 256, 0, stream>>>(ebuf, segs, rowptr, dis, csrc, n, NB, E);

  // 4. XCD-sliced layer-1 aggregate + epilogue -> hbf (fp16)
  //    slice = blockIdx % 8 pins each 3.2MB feature slice to one XCD's L2.
  const int nodeblocks = (n + 127) / 128;
  k_gslice<<<8 * nodeblocks, 256, 0, stream>>>(rowptr, csrc, dis, h1f,
                                               b1, pa, hbf, n, dk1_0, dk1_1);

  // 5. h2 = h @ W2 (MFMA f16, unscaled fp16 out)
  k_gemm2<<<(n + 63) / 64, 256, 0, stream>>>(hbf, W2, h2f, n);

  // 6. layer-2 aggregate + epilogue + fused gemm3 -> out
  k_gather2<<<(n * 8 + 255) / 256, 256, 0, stream>>>(rowptr, csrc, dis, h2f,
                                                     b2, pa, Wfc, bfc, out, n,
                                                     dk2_0, dk2_1);
}

// Round 16
// 164.428 us; speedup vs baseline: 2.1870x; 2.1870x over previous
//
#include <hip/hip_runtime.h>
#include <stdint.h>

#define G1  128   // blocks for hist/scatter passes
#define BSH 9     // log2(nodes per bucket)
#define BSZ 512   // nodes per bucket
// NB = ceil(n/512) must be <= 256 (holds for n <= 131072; here n = 100000 -> 196)

typedef __attribute__((ext_vector_type(8))) _Float16 f16x8;
typedef __attribute__((ext_vector_type(2))) _Float16 f16x2;
typedef __attribute__((ext_vector_type(2))) __fp16 fp16x2r;  // cvt_pkrtz return type
typedef __attribute__((ext_vector_type(4))) float f32x4;

// ---------------- threefry2x32 (JAX-compatible, 20 rounds) ----------------
#define TF_ROUND(x0, x1, r)                                                    \
  {                                                                            \
    x0 += x1;                                                                  \
    x1 = (x1 << r) | (x1 >> (32 - r));                                         \
    x1 ^= x0;                                                                  \
  }

__host__ __device__ inline void threefry2x32(uint32_t k0, uint32_t k1,
                                             uint32_t x0, uint32_t x1,
                                             uint32_t* o0, uint32_t* o1) {
  uint32_t ks2 = k0 ^ k1 ^ 0x1BD11BDAu;
  x0 += k0; x1 += k1;
  TF_ROUND(x0, x1, 13) TF_ROUND(x0, x1, 15) TF_ROUND(x0, x1, 26) TF_ROUND(x0, x1, 6)
  x0 += k1; x1 += ks2 + 1u;
  TF_ROUND(x0, x1, 17) TF_ROUND(x0, x1, 29) TF_ROUND(x0, x1, 16) TF_ROUND(x0, x1, 24)
  x0 += ks2; x1 += k0 + 2u;
  TF_ROUND(x0, x1, 13) TF_ROUND(x0, x1, 15) TF_ROUND(x0, x1, 26) TF_ROUND(x0, x1, 6)
  x0 += k0; x1 += k1 + 3u;
  TF_ROUND(x0, x1, 17) TF_ROUND(x0, x1, 29) TF_ROUND(x0, x1, 16) TF_ROUND(x0, x1, 24)
  x0 += k1; x1 += ks2 + 4u;
  TF_ROUND(x0, x1, 13) TF_ROUND(x0, x1, 15) TF_ROUND(x0, x1, 26) TF_ROUND(x0, x1, 6)
  x0 += ks2; x1 += k0 + 5u;
  *o0 = x0; *o1 = x1;
}

__device__ inline uint32_t tf_bits32(uint32_t k0, uint32_t k1, uint32_t ctr) {
  uint32_t a, b;
  threefry2x32(k0, k1, 0u, ctr, &a, &b);
  return a ^ b;
}

// fp16 helpers
__device__ inline f16x2 u2h(uint32_t u) {
  union { uint32_t u; f16x2 h; } c; c.u = u; return c.h;
}
__device__ inline uint32_t h2u(f16x2 h) {
  union { uint32_t u; f16x2 h; } c; c.h = h; return c.u;
}
__device__ inline uint32_t pk2h(float a, float b) {
  union { fp16x2r h; uint32_t u; } c;
  c.h = __builtin_amdgcn_cvt_pkrtz(a, b);
  return c.u;
}
__device__ inline uint16_t f2h(float a) {
  union { fp16x2r h; uint32_t u; } c;
  c.h = __builtin_amdgcn_cvt_pkrtz(a, 0.f);
  return (uint16_t)c.u;
}

// ---- histogram only: per-block dst-bucket counts -> hist_t[bucket][block] ----
__global__ __launch_bounds__(256) void k_hist(const int* __restrict__ dst,
                                              int* __restrict__ hist_t,
                                              int E, int NB, int chunk) {
  __shared__ int hist[256];
  const int tid = threadIdx.x;
  for (int b = tid; b < NB; b += 256) hist[b] = 0;
  __syncthreads();
  int e0 = blockIdx.x * chunk;
  int e1 = min(e0 + chunk, E);
  for (int e = e0 + tid; e < e1; e += 256)
    atomicAdd(&hist[dst[e] >> BSH], 1);
  __syncthreads();
  for (int b = tid; b < NB; b += 256)
    hist_t[b * G1 + blockIdx.x] = hist[b];
}

// ---- merged: blocks 0..G1-1 = bscatter (self-scan); blocks G1.. = GEMM1 ----
__global__ __launch_bounds__(256) void k_bsc_gemm1(
    const int* __restrict__ src, const int* __restrict__ dst,
    const int* __restrict__ hist_t, int* __restrict__ segs,
    uint32_t* __restrict__ ebuf, int E, int NB, int chunk,
    const float* __restrict__ x, const float* __restrict__ W,
    uint16_t* __restrict__ h, int n) {
  __shared__ char smem[(64 * 136 + 128 * 136) * 2];
  const int tid = threadIdx.x;
  if (blockIdx.x < G1) {
    int* rowsum = (int*)smem;
    int* cur = ((int*)smem) + 256;
    const int g = blockIdx.x;
    int rs = 0, ps = 0;
    if (tid < NB) {
      const int* row = hist_t + tid * G1;
      for (int i = 0; i < G1; ++i) {
        int v = row[i];
        rs += v;
        if (i < g) ps += v;
      }
    }
    rowsum[tid] = rs;
    __syncthreads();
    for (int off = 1; off < 256; off <<= 1) {
      int tmp = (tid >= off) ? rowsum[tid - off] : 0;
      __syncthreads();
      rowsum[tid] += tmp;
      __syncthreads();
    }
    int rb = rowsum[tid] - rs;  // exclusive row base
    if (tid < NB) cur[tid] = rb + ps;
    if (g == 0) {
      if (tid < NB) segs[tid] = rb;
      if (tid == 255) segs[NB] = rowsum[255];  // total = E
    }
    __syncthreads();
    int e0 = g * chunk, e1 = min(e0 + chunk, E);
    for (int e = e0 + tid; e < e1; e += 256) {
      int d = dst[e];
      int slot = atomicAdd(&cur[d >> BSH], 1);
      ebuf[slot] = ((uint32_t)src[e] << BSH) | (uint32_t)(d & (BSZ - 1));
    }
    return;
  }
  // ---- GEMM1 part ----
  uint16_t (*As)[136] = (uint16_t(*)[136])smem;
  uint16_t (*Bs)[136] = (uint16_t(*)[136])(smem + 64 * 136 * 2);
  const int rowBase = (blockIdx.x - G1) * 64;
  for (int i = tid; i < 64 * 32; i += 256) {
    int r = i >> 5, c4 = i & 31;
    float4 v = make_float4(0.f, 0.f, 0.f, 0.f);
    if (rowBase + r < n)
      v = ((const float4*)(x + (size_t)(rowBase + r) * 128))[c4];
    *(uint2*)&As[r][c4 * 4] = make_uint2(pk2h(v.x, v.y), pk2h(v.z, v.w));
  }
  {
    int k2 = tid >> 7;
    int c = tid & 127;
    for (int kk = 0; kk < 128; kk += 4) {
      int k = kk + k2 * 2;
      *(uint32_t*)&Bs[c][k] = pk2h(W[k * 128 + c], W[(k + 1) * 128 + c]);
    }
  }
  __syncthreads();
  const int wid = tid >> 6;
  const int lane = tid & 63;
  const int l15 = lane & 15;
  const int lhi = lane >> 4;
  f32x4 acc[8];
#pragma unroll
  for (int t = 0; t < 8; ++t) acc[t] = (f32x4){0.f, 0.f, 0.f, 0.f};
  const int arow = wid * 16 + l15;
#pragma unroll
  for (int ks = 0; ks < 4; ++ks) {
    f16x8 a = *(f16x8*)&As[arow][ks * 32 + lhi * 8];
#pragma unroll
    for (int ct = 0; ct < 8; ++ct) {
      f16x8 bfrag = *(f16x8*)&Bs[ct * 16 + l15][ks * 32 + lhi * 8];
      acc[ct] = __builtin_amdgcn_mfma_f32_16x16x32_f16(a, bfrag, acc[ct], 0, 0, 0);
    }
  }
#pragma unroll
  for (int j = 0; j < 4; ++j) {
    int row = rowBase + wid * 16 + lhi * 4 + j;
    if (row < n) {
#pragma unroll
      for (int ct = 0; ct < 8; ++ct)
        h[(size_t)row * 128 + ct * 16 + l15] = f2h(acc[ct][j]);
    }
  }
}

// ---- bfinal: 512 threads, one node per thread ----
__global__ __launch_bounds__(512) void k_bfinal(const uint32_t* __restrict__ ebuf,
                                                const int* __restrict__ segs,
                                                int* __restrict__ rowptr,
                                                float* __restrict__ dis,
                                                int* __restrict__ csrc,
                                                int n, int NB, int E) {
  __shared__ int cnt[BSZ];
  __shared__ int sc[BSZ];
  int b = blockIdx.x;
  int t = threadIdx.x;
  int seg0 = segs[b];
  int seg1 = segs[b + 1];
  cnt[t] = 0;
  __syncthreads();
  for (int i = seg0 + t; i < seg1; i += 512)
    atomicAdd(&cnt[ebuf[i] & (BSZ - 1)], 1);
  __syncthreads();
  int own = cnt[t];
  sc[t] = own;
  __syncthreads();
  for (int off = 1; off < 512; off <<= 1) {
    int tmp = (t >= off) ? sc[t - off] : 0;
    __syncthreads();
    sc[t] += tmp;
    __syncthreads();
  }
  int pre = sc[t] - own;  // exclusive
  int nd = b * BSZ + t;
  int p = seg0 + pre;
  if (nd <= n) rowptr[nd] = p;
  if (nd < n) dis[nd] = rsqrtf((float)(own + 1));
  cnt[t] = p;  // cursor
  if (b == NB - 1 && t == 0) rowptr[n] = E;
  __syncthreads();
  for (int i = seg0 + t; i < seg1; i += 512) {
    uint32_t u = ebuf[i];
    int slot = atomicAdd(&cnt[u & (BSZ - 1)], 1);
    csrc[slot] = (int)(u >> BSH);
  }
}

// ---- FUSED gather1 + gemm2: block = 16 nodes (4 waves x 4 sequential nodes).
// Inner loop MLP=4 (R11 best config).
__global__ __launch_bounds__(256) void k_gather12(
    const int* __restrict__ rowptr, const int* __restrict__ csrc,
    const float* __restrict__ dis, const uint16_t* __restrict__ h1,
    const float* __restrict__ bias, const float* __restrict__ pa,
    const float* __restrict__ W2, uint32_t* __restrict__ h2,
    int n, uint32_t k0, uint32_t k1) {
  __shared__ uint16_t hs[16][136];  // post-dropout h rows (fp16)
  __shared__ uint16_t Bs[16][136];  // W2 staged [col][k]
  const int tid = threadIdx.x;
  {
    int c = tid & 15;
    int k8 = tid >> 4;
#pragma unroll
    for (int jj = 0; jj < 8; ++jj) {
      int k = k8 * 8 + jj;
      Bs[c][k] = f2h(W2[k * 16 + c]);
    }
  }
  const int wid = tid >> 6;
  const int lane = tid & 63;
  const int q = lane >> 4;
  const int sl = lane & 15;
  const int f0 = 8 * sl + 2 * q;
  const int base = blockIdx.x * 16;
  const uint4* rowbase = (const uint4*)h1;  // 16B units, 16 per row
  const float a = pa[0];
  const float bi0 = bias[f0];
  const float bi1 = bias[f0 + 1];
  for (int i = 0; i < 4; ++i) {
    const int nrow = wid * 4 + i;
    const int v = base + nrow;
    if (v < n) {
      uint32_t jj = (uint32_t)v * 128u + (uint32_t)f0;
      uint32_t bits0 = tf_bits32(k0, k1, jj);
      uint32_t bits1 = tf_bits32(k0, k1, jj + 1);
      float dv = dis[v];
      f16x2 acc0 = u2h(0u), acc1 = u2h(0u), acc2 = u2h(0u), acc3 = u2h(0u);
      if (q == 0) {  // self term with weight dv
        uint4 r = rowbase[(size_t)v * 16 + sl];
        f16x2 w = u2h(pk2h(dv, dv));
        acc0 += u2h(r.x) * w; acc1 += u2h(r.y) * w;
        acc2 += u2h(r.z) * w; acc3 += u2h(r.w) * w;
      }
      int beg = rowptr[v];
      int deg = rowptr[v + 1] - beg;
      for (int bb = 0; bb < deg; bb += 64) {
        int cnt = min(64, deg - bb);
        int idx = bb + lane;
        int sv = v;          // padded edges: own row (L1 hit), zero weight
        uint32_t wpk = 0u;
        if (idx < deg) {
          sv = csrc[beg + idx];
          float wd = dis[sv];
          wpk = pk2h(wd, wd);
        }
        for (int j = 0; j < cnt; j += 16) {
          int s0 = __shfl(sv, j + q);
          int s1 = __shfl(sv, j + 4 + q);
          int s2 = __shfl(sv, j + 8 + q);
          int s3 = __shfl(sv, j + 12 + q);
          uint32_t w0 = (uint32_t)__shfl((int)wpk, j + q);
          uint32_t w1 = (uint32_t)__shfl((int)wpk, j + 4 + q);
          uint32_t w2 = (uint32_t)__shfl((int)wpk, j + 8 + q);
          uint32_t w3 = (uint32_t)__shfl((int)wpk, j + 12 + q);
          uint4 r0 = rowbase[(size_t)s0 * 16 + sl];
          uint4 r1 = rowbase[(size_t)s1 * 16 + sl];
          uint4 r2 = rowbase[(size_t)s2 * 16 + sl];
          uint4 r3 = rowbase[(size_t)s3 * 16 + sl];
          f16x2 hw0 = u2h(w0), hw1 = u2h(w1), hw2 = u2h(w2), hw3 = u2h(w3);
          acc0 += u2h(r0.x) * hw0; acc1 += u2h(r0.y) * hw0;
          acc2 += u2h(r0.z) * hw0; acc3 += u2h(r0.w) * hw0;
          acc0 += u2h(r1.x) * hw1; acc1 += u2h(r1.y) * hw1;
          acc2 += u2h(r1.z) * hw1; acc3 += u2h(r1.w) * hw1;
          acc0 += u2h(r2.x) * hw2; acc1 += u2h(r2.y) * hw2;
          acc2 += u2h(r2.z) * hw2; acc3 += u2h(r2.w) * hw2;
          acc0 += u2h(r3.x) * hw3; acc1 += u2h(r3.y) * hw3;
          acc2 += u2h(r3.z) * hw3; acc3 += u2h(r3.w) * hw3;
        }
      }
#define COMB(A)                                                                \
  {                                                                            \
    uint32_t u_ = h2u(A);                                                      \
    A = A + u2h((uint32_t)__shfl_xor((int)u_, 16));                            \
    u_ = h2u(A);                                                               \
    A = A + u2h((uint32_t)__shfl_xor((int)u_, 32));                            \
  }
      COMB(acc0) COMB(acc1) COMB(acc2) COMB(acc3)
#undef COMB
      f16x2 p = (q == 0) ? acc0 : (q == 1) ? acc1 : (q == 2) ? acc2 : acc3;
      float v0 = (float)p.x * dv + bi0;
      float v1 = (float)p.y * dv + bi1;
      v0 = v0 >= 0.f ? v0 : a * v0;
      v1 = v1 >= 0.f ? v1 : a * v1;
      float r0 = (bits0 & 0x80000000u) ? 0.f : 2.f * v0;
      float r1 = (bits1 & 0x80000000u) ? 0.f : 2.f * v1;
      *(uint32_t*)&hs[nrow][f0] = pk2h(r0, r1);
    } else {
      *(uint32_t*)&hs[nrow][f0] = 0u;
    }
  }
  __syncthreads();
  // ---- gemm2 tile: h2[16 nodes][16 feats] = hs @ W2 (wave 0 only) ----
  if (wid == 0) {
    const int l15 = lane & 15;
    const int lhi = lane >> 4;
    f32x4 acc = (f32x4){0.f, 0.f, 0.f, 0.f};
#pragma unroll
    for (int ks = 0; ks < 4; ++ks) {
      f16x8 af = *(f16x8*)&hs[l15][ks * 32 + lhi * 8];
      f16x8 bf = *(f16x8*)&Bs[l15][ks * 32 + lhi * 8];
      acc = __builtin_amdgcn_mfma_f32_16x16x32_f16(af, bf, acc, 0, 0, 0);
    }
#pragma unroll
    for (int j = 0; j < 4; ++j) {
      int gnode = base + lhi * 4 + j;
      float val = acc[j];
      float pv = __shfl_xor(val, 1);  // partner column, same row
      if (gnode < n && (l15 & 1) == 0)
        h2[(size_t)gnode * 8 + (l15 >> 1)] = pk2h(val, pv);
    }
  }
}

// ---- gather layer 2: 16 lanes/node (8 edge slots x 2 row-halves), MLP=8,
// packed-fp16 accs + fused GEMM3 ----
__global__ __launch_bounds__(256) void k_gather2(
    const int* __restrict__ rowptr, const int* __restrict__ csrc,
    const float* __restrict__ dis, const uint32_t* __restrict__ h2,
    const float* __restrict__ bias, const float* __restrict__ pa,
    const float* __restrict__ Wfc, const float* __restrict__ bfc,
    float* __restrict__ out, int n, uint32_t k0, uint32_t k1) {
  __shared__ float wfc[16][10];
  __shared__ float sbfc[10];
  __shared__ float sval[16][16];
  const int tid = threadIdx.x;
  if (tid < 160) ((float*)wfc)[tid] = Wfc[tid];
  if (tid < 10) sbfc[tid] = bfc[tid];
  __syncthreads();
  const int gnode = (blockIdx.x * 256 + tid) >> 4;
  const int grp = tid >> 4;        // node slot in block (0..15)
  const int sub = tid & 15;        // lane within node group
  const int q = sub >> 1;          // edge slot 0..7
  const int sl = sub & 1;          // row half (16B)
  const uint4* rowbase = (const uint4*)h2;  // 16B units, 2 per row
  if (gnode < n) {
    float dv = dis[gnode];
    f16x2 acc0 = u2h(0u), acc1 = u2h(0u), acc2 = u2h(0u), acc3 = u2h(0u);
    if (q == 0) {  // self term with weight dv
      uint4 r = rowbase[(size_t)gnode * 2 + sl];
      f16x2 w = u2h(pk2h(dv, dv));
      acc0 += u2h(r.x) * w; acc1 += u2h(r.y) * w;
      acc2 += u2h(r.z) * w; acc3 += u2h(r.w) * w;
    }
    int beg = rowptr[gnode];
    int deg = rowptr[gnode + 1] - beg;
    for (int bb = 0; bb < deg; bb += 16) {
      int cnt = min(16, deg - bb);
      int idx = bb + sub;
      int sv = gnode;       // padded: own row, zero weight
      uint32_t wpk = 0u;
      if (idx < deg) {
        sv = csrc[beg + idx];
        float wd = dis[sv];
        wpk = pk2h(wd, wd);
      }
      for (int j = 0; j < cnt; j += 8) {
        int s0 = __shfl(sv, j + q, 16);
        uint32_t w0 = (uint32_t)__shfl((int)wpk, j + q, 16);
        uint4 r0 = rowbase[(size_t)s0 * 2 + sl];
        f16x2 hw0 = u2h(w0);
        acc0 += u2h(r0.x) * hw0; acc1 += u2h(r0.y) * hw0;
        acc2 += u2h(r0.z) * hw0; acc3 += u2h(r0.w) * hw0;
      }
    }
    // combine across the 8 edge slots (xor 2, 4, 8 within 16-lane group)
#define COMB2(A)                                                               \
  {                                                                            \
    uint32_t u_ = h2u(A);                                                      \
    A = A + u2h((uint32_t)__shfl_xor((int)u_, 2));                             \
    u_ = h2u(A);                                                               \
    A = A + u2h((uint32_t)__shfl_xor((int)u_, 4));                             \
    u_ = h2u(A);                                                               \
    A = A + u2h((uint32_t)__shfl_xor((int)u_, 8));                             \
  }
    COMB2(acc0) COMB2(acc1) COMB2(acc2) COMB2(acc3)
#undef COMB2
    if (q < 4) {
      const int f0 = sl * 8 + q * 2;  // feats f0, f0+1
      f16x2 p = (q == 0) ? acc0 : (q == 1) ? acc1 : (q == 2) ? acc2 : acc3;
      uint32_t c0 = (uint32_t)gnode * 16u + (uint32_t)f0;
      uint32_t bits0 = tf_bits32(k0, k1, c0);
      uint32_t bits1 = tf_bits32(k0, k1, c0 + 1);
      float a = pa[0];
      float v0 = (float)p.x * dv + bias[f0];
      float v1 = (float)p.y * dv + bias[f0 + 1];
      v0 = v0 >= 0.f ? v0 : a * v0;
      v1 = v1 >= 0.f ? v1 : a * v1;
      sval[grp][f0]     = (bits0 & 0x80000000u) ? 0.f : 2.f * v0;
      sval[grp][f0 + 1] = (bits1 & 0x80000000u) ? 0.f : 2.f * v1;
    }
  }
  __syncthreads();
  if (gnode < n && sub < 5) {
    int c = sub * 2;
    float o0 = sbfc[c], o1 = sbfc[c + 1];
#pragma unroll
    for (int k = 0; k < 16; ++k) {
      float hv = sval[grp][k];
      o0 += hv * wfc[k][c];
      o1 += hv * wfc[k][c + 1];
    }
    *(float2*)&out[(size_t)gnode * 10 + c] = make_float2(o0, o1);
  }
}

extern "C" void kernel_launch(void* const* d_in, const int* in_sizes, int n_in,
                              void* d_out, int out_size, void* d_ws, size_t ws_size,
                              hipStream_t stream) {
  const float* x   = (const float*)d_in[0];
  const int*   ei  = (const int*)d_in[1];
  const float* W1  = (const float*)d_in[2];
  const float* b1  = (const float*)d_in[3];
  const float* W2  = (const float*)d_in[4];
  const float* b2  = (const float*)d_in[5];
  const float* pa  = (const float*)d_in[6];
  const float* Wfc = (const float*)d_in[7];
  const float* bfc = (const float*)d_in[8];
  float* out = (float*)d_out;

  const int n = in_sizes[0] / 128;
  const int E = in_sizes[1] / 2;
  const int* src = ei;
  const int* dst = ei + E;

  const int NB = (n + BSZ - 1) / BSZ;   // <= 256 required (n <= 131072)
  const int T = NB * G1;
  const int chunk = (E + G1 - 1) / G1;
  (void)T;

  char* w = (char*)d_ws;
  auto alloc = [&](size_t bytes) {
    char* p = w;
    w += (bytes + 255) & ~(size_t)255;
    return p;
  };
  float* dis      = (float*)alloc((size_t)n * 4);
  int* rowptr     = (int*)alloc((size_t)(n + 1) * 4);
  int* hist_t     = (int*)alloc((size_t)(NB * G1 + 1) * 4);
  int* segs       = (int*)alloc((size_t)(NB + 1) * 4);
  uint32_t* ebuf  = (uint32_t*)alloc((size_t)E * 4);
  int* csrc       = (int*)alloc((size_t)E * 4);
  uint16_t* h1f   = (uint16_t*)alloc((size_t)n * 128 * 2);  // fp16 h1 (unscaled)
  uint32_t* h2f   = (uint32_t*)alloc((size_t)n * 8 * 4);    // fp16 h2 (packed x2)

  uint32_t dk1_0, dk1_1, dk2_0, dk2_1;
  threefry2x32(0u, 42u, 0u, 0u, &dk1_0, &dk1_1);
  threefry2x32(0u, 42u, 0u, 1u, &dk2_0, &dk2_1);

  // 1. dst-bucket histogram
  k_hist<<<G1, 256, 0, stream>>>(dst, hist_t, E, NB, chunk);
  // 2. {bscatter (self-scan, emits segs) || gemm1 (unscaled fp16)} one launch
  k_bsc_gemm1<<<G1 + (n + 63) / 64, 256, 0, stream>>>(
      src, dst, hist_t, segs, ebuf, E, NB, chunk, x, W1, h1f, n);
  // 3. finalize: rowptr, dis, csrc (512 threads, 1 node/thread)
  k_bfinal<<<NB, 512, 0, stream>>>(ebuf, segs, rowptr, dis, csrc, n, NB, E);

  // 4. fused layer-1 aggregate + bias/prelu/dropout(dk1) + gemm2 -> h2f
  k_gather12<<<(n + 15) / 16, 256, 0, stream>>>(rowptr, csrc, dis, h1f,
                                                b1, pa, W2, h2f, n, dk1_0, dk1_1);

  // 5. layer-2 aggregate (16 lanes/node) + epilogue + fused gemm3 -> out
  k_gather2<<<((size_t)n * 16 + 255) / 256, 256, 0, stream>>>(
      rowptr, csrc, dis, h2f, b2, pa, Wfc, bfc, out, n, dk2_0, dk2_1);
}